// Round 1
// baseline (109.401 us; speedup 1.0000x reference)
//
#include <hip/hip_runtime.h>

// Problem constants (from reference): B=1048576, M=8, K=3, R=8
#define M_N 8
#define K_N 3
#define R_N 8
// Per-rule packed params in d_ws: [cc[8] | inv_sigma[8] | cons[9] | pad..] = 32 floats
#define RULE_STRIDE 32

// One-block pre-kernel: gather c / inv_sigma through rules, copy consequents.
__global__ void anfis_precompute(const float* __restrict__ c,
                                 const float* __restrict__ log_sigma,
                                 const float* __restrict__ consequents,
                                 const int* __restrict__ rules,
                                 float* __restrict__ params) {
    int tid = threadIdx.x;
    if (tid < R_N * M_N) {                       // 64 threads: cc + inv_sigma
        int r = tid >> 3, m = tid & 7;
        int k = rules[r * M_N + m];
        float sig = expf(log_sigma[m * K_N + k]) + 1e-6f;
        params[r * RULE_STRIDE + m]       = c[m * K_N + k];
        params[r * RULE_STRIDE + 8 + m]   = 1.0f / sig;
    }
    if (tid < R_N * (M_N + 1)) {                 // 72 threads: consequents (R x 9)
        int r = tid / 9, j = tid - r * 9;
        params[r * RULE_STRIDE + 16 + j] = consequents[r * (M_N + 1) + j];
    }
}

__global__ __launch_bounds__(256) void anfis_main(
        const float* __restrict__ x,
        const float* __restrict__ params,   // uniform -> scalar loads
        float* __restrict__ out,
        int B) {
    int b = blockIdx.x * blockDim.x + threadIdx.x;
    if (b >= B) return;

    // Load this element's 8 features (two coalesced float4 loads)
    const float4* xp = (const float4*)(x + (size_t)b * M_N);
    float4 x0 = xp[0];
    float4 x1 = xp[1];
    float xv[M_N] = {x0.x, x0.y, x0.z, x0.w, x1.x, x1.y, x1.z, x1.w};

    float fir[R_N], yr[R_N];
    float fsum = 0.0f;
#pragma unroll
    for (int r = 0; r < R_N; ++r) {
        const float* p = params + r * RULE_STRIDE;  // compile-time offsets -> s_load
        float s = 0.0f;
        float acc = p[16];                           // bias
#pragma unroll
        for (int m = 0; m < M_N; ++m) {
            float t = (xv[m] - p[m]) * p[8 + m];
            s   = fmaf(t, t, s);
            acc = fmaf(p[17 + m], xv[m], acc);
        }
        // prod_m exp(-0.5 t^2) == exp(-0.5 * sum t^2)
        fir[r] = __expf(-0.5f * s);
        yr[r]  = acc;
        fsum  += fir[r];
    }

    float inv = 1.0f / (fsum + 1e-8f);
    float wn[R_N];
    float y = 0.0f;
#pragma unroll
    for (int r = 0; r < R_N; ++r) {
        wn[r] = fir[r] * inv;
        y = fmaf(wn[r], yr[r], y);
    }

    // Outputs concatenated: y[B] | w_norm[B*R] | y_r[B*R]
    out[b] = y;
    float4* wout = (float4*)(out + (size_t)B + (size_t)b * R_N);
    wout[0] = make_float4(wn[0], wn[1], wn[2], wn[3]);
    wout[1] = make_float4(wn[4], wn[5], wn[6], wn[7]);
    float4* yout = (float4*)(out + (size_t)B * (1 + R_N) + (size_t)b * R_N);
    yout[0] = make_float4(yr[0], yr[1], yr[2], yr[3]);
    yout[1] = make_float4(yr[4], yr[5], yr[6], yr[7]);
}

extern "C" void kernel_launch(void* const* d_in, const int* in_sizes, int n_in,
                              void* d_out, int out_size, void* d_ws, size_t ws_size,
                              hipStream_t stream) {
    const float* x           = (const float*)d_in[0];
    const float* c           = (const float*)d_in[1];
    const float* log_sigma   = (const float*)d_in[2];
    const float* consequents = (const float*)d_in[3];
    const int*   rules       = (const int*)d_in[4];
    float* out = (float*)d_out;
    float* params = (float*)d_ws;   // R_N * RULE_STRIDE floats = 1 KB

    int B = in_sizes[0] / M_N;

    anfis_precompute<<<1, 128, 0, stream>>>(c, log_sigma, consequents, rules, params);
    anfis_main<<<(B + 255) / 256, 256, 0, stream>>>(x, params, out, B);
}